// Round 15
// baseline (120.352 us; speedup 1.0000x reference)
//
#include <hip/hip_runtime.h>
#include <hip/hip_bf16.h>
#include <math.h>

// Problem constants (B=1)
#define TT   512
#define CEMB 768
#define NH   12
#define NKV  6
#define HD   64
#define KVC  (NKV*HD)   // 384

typedef short short8 __attribute__((ext_vector_type(8)));
typedef float floatx4 __attribute__((ext_vector_type(4)));

// fp32 pair -> packed bf16 (round-to-nearest via HW packed convert)
__device__ __forceinline__ unsigned pack_bf16(float lo, float hi){
  __hip_bfloat162 h = __float22bfloat162_rn(make_float2(lo, hi));
  return *reinterpret_cast<unsigned*>(&h);
}
__device__ __forceinline__ unsigned short bf16_rn(float f){
  unsigned u = __float_as_uint(f);
  u += 0x7FFFu + ((u>>16)&1u);
  return (unsigned short)(u>>16);
}

// ============================================================================
// K1: QKV GEMM via bf16 MFMA + block-local RoPE/RMS epilogue.
// A-fragments loaded DIRECT from global (per-lane 2xfloat4, X is L2-hot;
// same total bytes as staging, no LDS round-trip). B staged in dbuf LDS.
// Grid x: 0..191 = gemm tiles, 192..227 = Wp fragment-pack blocks.
// ============================================================================
__global__ void __launch_bounds__(256) gemm_qkv_mfma(
    const float* __restrict__ X,
    const float* __restrict__ Wq, const float* __restrict__ Wk, const float* __restrict__ Wv,
    const float* __restrict__ Wp,
    const float* __restrict__ cosb, const float* __restrict__ sinb,
    float* __restrict__ q, float* __restrict__ k, float* __restrict__ v,
    unsigned short* __restrict__ WpF){
  int bx = blockIdx.x;
  if (bx >= 192){
    int t0 = (bx-192)*256 + threadIdx.x;           // 0..9215
    for(int g=0; g<8; ++g){
      int u  = g*9216 + t0;                        // 0..73727
      int kp = u / 192;
      int n4 = (u - kp*192)*4;
      int kk = kp*2;
      float4 w0 = *(const float4*)&Wp[(size_t)kk*CEMB + n4];
      float4 w1 = *(const float4*)&Wp[(size_t)(kk+1)*CEMB + n4];
      int ks = kk>>5, qq = (kk>>3)&3, j = kk&7;    // j even
      #pragma unroll
      for(int i=0;i<4;i++){
        int n = n4+i, ct = n>>4, r = n&15;
        *(unsigned*)&WpF[ (((size_t)(ct*24 + ks)*64 + qq*16 + r)<<3) + j ] =
          pack_bf16((&w0.x)[i], (&w1.x)[i]);
      }
    }
    return;
  }
  int mt = bx / 24, nt = bx % 24;
  const float* W; int ldb, bcol;
  if (nt < 12)      { W = Wq; ldb = CEMB; bcol = nt*64; }
  else if (nt < 18) { W = Wk; ldb = KVC;  bcol = (nt-12)*64; }
  else              { W = Wv; ldb = KVC;  bcol = (nt-18)*64; }

  __shared__ __align__(16) unsigned short Bl[2][64][40];

  int tid = threadIdx.x;
  int bkp = tid>>4,  bn4 = (tid&15)*4;   // B stage: k-pair, 4 cols
  int w = tid>>6, lane = tid&63, qq = lane>>4, r = lane&15;

  floatx4 acc[4];
  #pragma unroll
  for(int c=0;c<4;c++) acc[c] = (floatx4){0.f,0.f,0.f,0.f};

  const float* Ax = X + (size_t)(mt*64 + w*16 + r)*CEMB + qq*8;  // per-lane A base
  const float* Bp = W + (size_t)(2*bkp)*ldb + bcol + bn4;

  float4 a0 = *(const float4*)(Ax);
  float4 a1 = *(const float4*)(Ax + 4);
  float4 b0 = *(const float4*)(Bp);
  float4 b1 = *(const float4*)(Bp + ldb);

  int buf = 0;
  for(int k0=0; k0<CEMB; k0+=32){
    // build A fragment from regs (before prefetch clobbers a0/a1)
    uint4 afu = make_uint4(pack_bf16(a0.x,a0.y), pack_bf16(a0.z,a0.w),
                           pack_bf16(a1.x,a1.y), pack_bf16(a1.z,a1.w));
    short8 af; __builtin_memcpy(&af, &afu, 16);
    // commit B tile to LDS[buf]
    #pragma unroll
    for(int i=0;i<4;i++)
      *(unsigned*)&Bl[buf][bn4+i][2*bkp] = pack_bf16((&b0.x)[i], (&b1.x)[i]);
    // prefetch next chunk
    if (k0 + 32 < CEMB){
      a0 = *(const float4*)(Ax + k0+32);
      a1 = *(const float4*)(Ax + k0+36);
      b0 = *(const float4*)(Bp + (size_t)(k0+32)*ldb);
      b1 = *(const float4*)(Bp + (size_t)(k0+33)*ldb);
    }
    __syncthreads();
    #pragma unroll
    for(int c=0;c<4;c++){
      short8 bf = *(short8*)&Bl[buf][c*16 + r][qq*8];
      acc[c] = __builtin_amdgcn_mfma_f32_16x16x32_bf16(af, bf, acc[c], 0,0,0);
    }
    buf ^= 1;
  }

  // epilogue: RoPE pairs d<->d+32 = acc c<->c+2 (same lane); RMS over 16 lanes.
  #pragma unroll
  for(int reg=0; reg<4; ++reg){
    int t = mt*64 + w*16 + qq*4 + reg;
    if (nt < 18){
      float cs0 = cosb[t*32 + r],      sn0 = sinb[t*32 + r];
      float cs1 = cosb[t*32 + 16 + r], sn1 = sinb[t*32 + 16 + r];
      float x0 = acc[0][reg], x1 = acc[1][reg], x2 = acc[2][reg], x3 = acc[3][reg];
      float n0 = x0*cs0 - x2*sn0;
      float n1 = x1*cs1 - x3*sn1;
      float n2 = x2*cs0 + x0*sn0;
      float n3 = x3*cs1 + x1*sn1;
      float ss = n0*n0 + n1*n1 + n2*n2 + n3*n3;
      ss += __shfl_xor(ss,1); ss += __shfl_xor(ss,2);
      ss += __shfl_xor(ss,4); ss += __shfl_xor(ss,8);
      float sc = rsqrtf(ss*(1.0f/64.0f) + 1e-6f);
      float* dst = (nt < 12) ? (q + (size_t)t*CEMB + nt*64)
                             : (k + (size_t)t*KVC + (nt-12)*64);
      dst[r]    = n0*sc; dst[16+r] = n1*sc;
      dst[32+r] = n2*sc; dst[48+r] = n3*sc;
    } else {
      float* dst = v + (size_t)t*KVC + (nt-18)*64;
      dst[r]    = acc[0][reg]; dst[16+r] = acc[1][reg];
      dst[32+r] = acc[2][reg]; dst[48+r] = acc[3][reg];
    }
  }
}

// ============================================================================
// K2: tropical attention, one 64x64 KV-tile per block. Scores: fp32 VALU
// (max-plus, at its VALU floor). PV: bf16 MFMA — P written to LDS in
// A-fragment layout, V staged transposed in B-fragment layout.
// ============================================================================
__global__ void __launch_bounds__(256) attn_tile(const float* __restrict__ qn,
    const float* __restrict__ kn, const float* __restrict__ vr,
    float* __restrict__ part_acc, float2* __restrict__ part_ml){
  __shared__ float Qsh[64*68];                          // Q (fp32, R12 layout)
  __shared__ float Ksh[64*64];                          // K fp32, XOR swizzle
  __shared__ __align__(16) unsigned short Pl[64][72];   // P bf16 [m][k], A-frag
  __shared__ __align__(16) unsigned short VshT[64][72]; // V^T bf16 [d][j], B-frag

  int h   = blockIdx.y;
  int idx = blockIdx.x;          // 0..35
  int qt = 0, rem = idx;
  while (rem > qt){ rem -= (qt+1); ++qt; }
  int ct = rem;                  // 0..qt
  int t0 = ct*64;

  int kvh  = h >> 1;
  int w    = threadIdx.x >> 6;
  int lane = threadIdx.x & 63;
  int lg   = lane >> 4;
  int lc   = lane & 15;

  #pragma unroll
  for(int sub=0; sub<4; ++sub){
    int rr = w*16 + sub*4 + lg;
    int sw = ((lc ^ (rr>>2)) & 15)*4;
    *(float4*)&Qsh[rr*68 + lc*4] =
      *(const float4*)&qn[(size_t)(qt*64+rr)*CEMB + h*HD + lc*4];
    *(float4*)&Ksh[rr*64 + sw] =
      *(const float4*)&kn[(size_t)(t0+rr)*KVC + kvh*HD + lc*4];
    float4 vf = *(const float4*)&vr[(size_t)(t0+rr)*KVC + kvh*HD + lc*4];
    VshT[lc*4+0][rr] = bf16_rn(vf.x);
    VshT[lc*4+1][rr] = bf16_rn(vf.y);
    VshT[lc*4+2][rr] = bf16_rn(vf.z);
    VshT[lc*4+3][rr] = bf16_rn(vf.w);
  }
  __syncthreads();

  // scores: s[r][c] = max_d q[row_r][d] + k[col_c][d]  (fp32 VALU floor)
  float s[4][4];
  #pragma unroll
  for(int r=0;r<4;r++)
    #pragma unroll
    for(int c=0;c<4;c++) s[r][c] = -INFINITY;

  #pragma unroll
  for(int dg=0; dg<16; ++dg){
    float4 k4[4], q4[4];
    int ksw = ((dg ^ lc)&15)*4;
    #pragma unroll
    for(int c=0;c<4;c++)
      k4[c] = *(const float4*)&Ksh[(lc*4+c)*64 + ksw];
    #pragma unroll
    for(int r=0;r<4;r++)
      q4[r] = *(const float4*)&Qsh[(w*16+lg*4+r)*68 + dg*4];
    #pragma unroll
    for(int r=0;r<4;r++)
      #pragma unroll
      for(int c=0;c<4;c++)
        s[r][c] = fmaxf(s[r][c],
                  fmaxf(fmaxf(q4[r].x + k4[c].x, q4[r].y + k4[c].y),
                        fmaxf(q4[r].z + k4[c].z, q4[r].w + k4[c].w)));
  }

  // per-row tile softmax; P -> Pl as bf16 (rows wave-private)
  #pragma unroll
  for(int r=0;r<4;r++){
    int i = qt*64 + w*16 + lg*4 + r;
    #pragma unroll
    for(int c=0;c<4;c++)
      if (t0 + lc*4 + c > i) s[r][c] = -INFINITY;   // causal mask
    float mt = fmaxf(fmaxf(s[r][0],s[r][1]), fmaxf(s[r][2],s[r][3]));
    mt = fmaxf(mt, __shfl_xor(mt,1));
    mt = fmaxf(mt, __shfl_xor(mt,2));
    mt = fmaxf(mt, __shfl_xor(mt,4));
    mt = fmaxf(mt, __shfl_xor(mt,8));
    float p0 = __expf(s[r][0]-mt), p1 = __expf(s[r][1]-mt);
    float p2 = __expf(s[r][2]-mt), p3 = __expf(s[r][3]-mt);
    float ps = p0+p1+p2+p3;
    ps += __shfl_xor(ps,1); ps += __shfl_xor(ps,2);
    ps += __shfl_xor(ps,4); ps += __shfl_xor(ps,8);
    *(uint2*)&Pl[w*16+lg*4+r][lc*4] =
      make_uint2(pack_bf16(p0,p1), pack_bf16(p2,p3));
    if (lc == 0)
      part_ml[(h*TT + i)*8 + ct] = make_float2(mt, ps);
  }
  __builtin_amdgcn_wave_barrier();   // DS in-order per wave; Pl rows wave-private

  // PV via MFMA: D[16 x 64] = P[16 x 64] * V[64 x 64], per wave strip.
  // a_frag: P[m=lc][k=lg*8+j]; b_frag: V^T[n-tile c][k]; two K=32 steps.
  floatx4 macc[4];
  #pragma unroll
  for(int c=0;c<4;c++) macc[c] = (floatx4){0.f,0.f,0.f,0.f};

  short8 af1 = *(short8*)&Pl[w*16 + lc][lg*8];
  short8 af2 = *(short8*)&Pl[w*16 + lc][32 + lg*8];
  #pragma unroll
  for(int c=0;c<4;c++){
    short8 bf1 = *(short8*)&VshT[c*16 + lc][lg*8];
    short8 bf2 = *(short8*)&VshT[c*16 + lc][32 + lg*8];
    macc[c] = __builtin_amdgcn_mfma_f32_16x16x32_bf16(af1, bf1, macc[c], 0,0,0);
    macc[c] = __builtin_amdgcn_mfma_f32_16x16x32_bf16(af2, bf2, macc[c], 0,0,0);
  }

  // write chunk partials: C-layout row = lg*4+reg, col = c*16+lc
  #pragma unroll
  for(int reg=0; reg<4; ++reg){
    int i = qt*64 + w*16 + lg*4 + reg;
    int pidx = (h*TT + i)*8 + ct;
    #pragma unroll
    for(int c=0;c<4;c++)
      part_acc[(size_t)pidx*64 + c*16 + lc] = macc[c][reg];
  }
}

// ============================================================================
// K3: merge <=8 chunk partials per (h,row) -> yF bf16 A-fragments. (R12-proven)
// ============================================================================
__global__ void __launch_bounds__(256) attn_reduce(const float* __restrict__ part_acc,
    const float2* __restrict__ part_ml, unsigned short* __restrict__ yF){
  int wid  = (blockIdx.x * blockDim.x + threadIdx.x) >> 6;  // 0..6143
  int lane = threadIdx.x & 63;
  int h = wid >> 9;
  int i = wid & 511;
  int nch = (i >> 6) + 1;       // wave-uniform
  int base = (h*TT + i)*8;

  float2 mls[8]; float acs[8];
  #pragma unroll
  for(int c=0;c<8;c++){
    mls[c] = part_ml[base + c];
    acs[c] = part_acc[(size_t)(base + c)*64 + lane];
  }

  float m = -INFINITY, l = 0.f, a = 0.f;
  #pragma unroll
  for(int c=0;c<8;c++){
    if (c < nch){
      float m_new = fmaxf(m, mls[c].x);
      float sa  = __expf(m - m_new);
      float sc_ = __expf(mls[c].x - m_new);
      l = l*sa + mls[c].y*sc_;
      a = a*sa + acs[c]*sc_;
      m = m_new;
    }
  }
  float val = a / l;
  int s = i>>4, rr = i&15;
  int ks = h*2 + (lane>>5), q2 = (lane>>3)&3, j = lane&7;
  yF[ (((size_t)(s*24 + ks)*64 + q2*16 + rr)<<3) + j ] = bf16_rn(val);
}

// ============================================================================
// K4: proj GEMM, fragment-direct, 192 blocks (8mt x 24 ntH of 32 cols).
// (R12-proven)
// ============================================================================
__global__ void __launch_bounds__(256) gemm_proj_mfma(
    const unsigned short* __restrict__ yF, const unsigned short* __restrict__ WpF,
    float* __restrict__ out){
  int bx = blockIdx.x;           // 0..191
  int mt = bx / 24, ntH = bx % 24;
  int tid = threadIdx.x, w = tid>>6, lane = tid&63, qq = lane>>4, r = lane&15;
  int s = mt*4 + w;   // 16-row strip

  const short8* Af = (const short8*)yF  + (size_t)s*24*64 + lane;
  const short8* Bf = (const short8*)WpF + lane;

  floatx4 acc[2];
  acc[0] = (floatx4){0.f,0.f,0.f,0.f};
  acc[1] = (floatx4){0.f,0.f,0.f,0.f};

  short8 ac_ = Af[0];
  short8 bc_[2];
  #pragma unroll
  for(int c=0;c<2;c++) bc_[c] = Bf[(size_t)((ntH*2+c)*24)*64];

  for(int ks=0; ks<24; ++ks){
    short8 an; short8 bn[2];
    if (ks < 23){
      an = Af[(size_t)(ks+1)*64];
      #pragma unroll
      for(int c=0;c<2;c++) bn[c] = Bf[(size_t)((ntH*2+c)*24 + ks+1)*64];
    }
    #pragma unroll
    for(int c=0;c<2;c++)
      acc[c] = __builtin_amdgcn_mfma_f32_16x16x32_bf16(ac_, bc_[c], acc[c], 0,0,0);
    if (ks < 23){
      ac_ = an;
      #pragma unroll
      for(int c=0;c<2;c++) bc_[c] = bn[c];
    }
  }

  #pragma unroll
  for(int reg=0; reg<4; ++reg){
    int t = mt*64 + w*16 + qq*4 + reg;
    float* dst = out + (size_t)t*CEMB + ntH*32;
    #pragma unroll
    for(int c=0;c<2;c++)
      dst[c*16 + r] = acc[c][reg];
  }
}

extern "C" void kernel_launch(void* const* d_in, const int* in_sizes, int n_in,
                              void* d_out, int out_size, void* d_ws, size_t ws_size,
                              hipStream_t stream){
  const float* x    = (const float*)d_in[0];
  const float* cosb = (const float*)d_in[1];
  const float* sinb = (const float*)d_in[2];
  const float* Wq   = (const float*)d_in[3];
  const float* Wk   = (const float*)d_in[4];
  const float* Wv   = (const float*)d_in[5];
  const float* Wp   = (const float*)d_in[6];
  float* out = (float*)d_out;

  float* ws        = (float*)d_ws;
  float* q_raw     = ws;                                // 512*768
  float* k_raw     = q_raw + (size_t)TT*CEMB;           // 512*384
  float* v_raw     = k_raw + (size_t)TT*KVC;            // 512*384
  float* part_acc  = v_raw + (size_t)TT*KVC;            // 12*512*8*64
  float2* part_ml  = (float2*)(part_acc + (size_t)NH*TT*8*64);  // 12*512*8
  unsigned short* WpF = (unsigned short*)(part_ml + (size_t)NH*TT*8); // 48*24*64*8
  unsigned short* yF  = WpF + (size_t)48*24*64*8;       // 32*24*64*8

  gemm_qkv_mfma <<<dim3(228),   256, 0, stream>>>(x, Wq, Wk, Wv, Wp, cosb, sinb,
                                                  q_raw, k_raw, v_raw, WpF);
  attn_tile     <<<dim3(36,NH), 256, 0, stream>>>(q_raw, k_raw, v_raw, part_acc, part_ml);
  attn_reduce   <<<dim3(NH*TT/4), 256, 0, stream>>>(part_acc, part_ml, yF);
  gemm_proj_mfma<<<dim3(192),   256, 0, stream>>>(yF, WpF, out);
}

// Round 16
// 115.160 us; speedup vs baseline: 1.0451x; 1.0451x over previous
//
#include <hip/hip_runtime.h>
#include <hip/hip_bf16.h>
#include <math.h>

// Problem constants (B=1)
#define TT   512
#define CEMB 768
#define NH   12
#define NKV  6
#define HD   64
#define KVC  (NKV*HD)   // 384

typedef short short8 __attribute__((ext_vector_type(8)));
typedef float floatx4 __attribute__((ext_vector_type(4)));

// fp32 pair -> packed bf16 (round-to-nearest via HW packed convert)
__device__ __forceinline__ unsigned pack_bf16(float lo, float hi){
  __hip_bfloat162 h = __float22bfloat162_rn(make_float2(lo, hi));
  return *reinterpret_cast<unsigned*>(&h);
}
__device__ __forceinline__ unsigned short bf16_rn(float f){
  unsigned u = __float_as_uint(f);
  u += 0x7FFFu + ((u>>16)&1u);
  return (unsigned short)(u>>16);
}
__device__ __forceinline__ float bf16_to_f32(unsigned short u){
  return __uint_as_float(((unsigned)u) << 16);
}

// ============================================================================
// K1: QKV GEMM via bf16 MFMA (no split-K) + block-local RoPE/RMS epilogue.
// Grid x: 0..191 = gemm tiles, 192..227 = Wp fragment-pack blocks. (R12-proven)
// ============================================================================
__global__ void __launch_bounds__(256) gemm_qkv_mfma(
    const float* __restrict__ X,
    const float* __restrict__ Wq, const float* __restrict__ Wk, const float* __restrict__ Wv,
    const float* __restrict__ Wp,
    const float* __restrict__ cosb, const float* __restrict__ sinb,
    float* __restrict__ q, float* __restrict__ k, float* __restrict__ v,
    unsigned short* __restrict__ WpF){
  int bx = blockIdx.x;
  if (bx >= 192){
    int t0 = (bx-192)*256 + threadIdx.x;           // 0..9215
    for(int g=0; g<8; ++g){
      int u  = g*9216 + t0;                        // 0..73727
      int kp = u / 192;
      int n4 = (u - kp*192)*4;
      int kk = kp*2;
      float4 w0 = *(const float4*)&Wp[(size_t)kk*CEMB + n4];
      float4 w1 = *(const float4*)&Wp[(size_t)(kk+1)*CEMB + n4];
      int ks = kk>>5, qq = (kk>>3)&3, j = kk&7;    // j even
      #pragma unroll
      for(int i=0;i<4;i++){
        int n = n4+i, ct = n>>4, r = n&15;
        *(unsigned*)&WpF[ (((size_t)(ct*24 + ks)*64 + qq*16 + r)<<3) + j ] =
          pack_bf16((&w0.x)[i], (&w1.x)[i]);
      }
    }
    return;
  }
  int mt = bx / 24, nt = bx % 24;
  const float* W; int ldb, bcol;
  if (nt < 12)      { W = Wq; ldb = CEMB; bcol = nt*64; }
  else if (nt < 18) { W = Wk; ldb = KVC;  bcol = (nt-12)*64; }
  else              { W = Wv; ldb = KVC;  bcol = (nt-18)*64; }

  __shared__ __align__(16) unsigned short Al[2][64][40];
  __shared__ __align__(16) unsigned short Bl[2][64][40];

  int tid = threadIdx.x;
  int am  = tid>>2,  akg = (tid&3)*8;
  int bkp = tid>>4,  bn4 = (tid&15)*4;
  int w = tid>>6, lane = tid&63, qq = lane>>4, r = lane&15;

  floatx4 acc[4];
  #pragma unroll
  for(int c=0;c<4;c++) acc[c] = (floatx4){0.f,0.f,0.f,0.f};

  const float* Ap = X + (size_t)(mt*64 + am)*CEMB + akg;
  const float* Bp = W + (size_t)(2*bkp)*ldb + bcol + bn4;

  float4 a0 = *(const float4*)(Ap);
  float4 a1 = *(const float4*)(Ap + 4);
  float4 b0 = *(const float4*)(Bp);
  float4 b1 = *(const float4*)(Bp + ldb);

  int buf = 0;
  for(int k0=0; k0<CEMB; k0+=32){
    unsigned p0 = pack_bf16(a0.x,a0.y), p1 = pack_bf16(a0.z,a0.w);
    unsigned p2 = pack_bf16(a1.x,a1.y), p3 = pack_bf16(a1.z,a1.w);
    *(uint4*)&Al[buf][am][akg] = make_uint4(p0,p1,p2,p3);
    #pragma unroll
    for(int i=0;i<4;i++)
      *(unsigned*)&Bl[buf][bn4+i][2*bkp] = pack_bf16((&b0.x)[i], (&b1.x)[i]);
    if (k0 + 32 < CEMB){
      a0 = *(const float4*)(Ap + k0+32);
      a1 = *(const float4*)(Ap + k0+36);
      b0 = *(const float4*)(Bp + (size_t)(k0+32)*ldb);
      b1 = *(const float4*)(Bp + (size_t)(k0+33)*ldb);
    }
    __syncthreads();
    short8 af = *(short8*)&Al[buf][w*16 + r][qq*8];
    #pragma unroll
    for(int c=0;c<4;c++){
      short8 bf = *(short8*)&Bl[buf][c*16 + r][qq*8];
      acc[c] = __builtin_amdgcn_mfma_f32_16x16x32_bf16(af, bf, acc[c], 0,0,0);
    }
    buf ^= 1;
  }

  // epilogue: RoPE pairs d<->d+32 = acc c<->c+2 (same lane); RMS over 16 lanes.
  #pragma unroll
  for(int reg=0; reg<4; ++reg){
    int t = mt*64 + w*16 + qq*4 + reg;
    if (nt < 18){
      float cs0 = cosb[t*32 + r],      sn0 = sinb[t*32 + r];
      float cs1 = cosb[t*32 + 16 + r], sn1 = sinb[t*32 + 16 + r];
      float x0 = acc[0][reg], x1 = acc[1][reg], x2 = acc[2][reg], x3 = acc[3][reg];
      float n0 = x0*cs0 - x2*sn0;
      float n1 = x1*cs1 - x3*sn1;
      float n2 = x2*cs0 + x0*sn0;
      float n3 = x3*cs1 + x1*sn1;
      float ss = n0*n0 + n1*n1 + n2*n2 + n3*n3;
      ss += __shfl_xor(ss,1); ss += __shfl_xor(ss,2);
      ss += __shfl_xor(ss,4); ss += __shfl_xor(ss,8);
      float sc = rsqrtf(ss*(1.0f/64.0f) + 1e-6f);
      float* dst = (nt < 12) ? (q + (size_t)t*CEMB + nt*64)
                             : (k + (size_t)t*KVC + (nt-12)*64);
      dst[r]    = n0*sc; dst[16+r] = n1*sc;
      dst[32+r] = n2*sc; dst[48+r] = n3*sc;
    } else {
      float* dst = v + (size_t)t*KVC + (nt-18)*64;
      dst[r]    = acc[0][reg]; dst[16+r] = acc[1][reg];
      dst[32+r] = acc[2][reg]; dst[48+r] = acc[3][reg];
    }
  }
}

// ============================================================================
// K2: tropical attention, one 64x64 KV-tile per block (R12-proven structure:
// fp32 Q/K/V in LDS, QPsh stride-68 reuse for P, fp32 VALU PV).
// Only change vs R12: chunk partials written as packed bf16 (halves the
// part_acc round-trip to K3: 12.6 -> 6.3 MB).
// ============================================================================
__global__ void __launch_bounds__(256) attn_tile(const float* __restrict__ qn,
    const float* __restrict__ kn, const float* __restrict__ vr,
    unsigned short* __restrict__ part_acc, float2* __restrict__ part_ml){
  __shared__ float QPsh[64*68];
  __shared__ float Ksh[64*64];
  __shared__ float Vsh[64*64];

  int h   = blockIdx.y;
  int idx = blockIdx.x;          // 0..35
  int qt = 0, rem = idx;
  while (rem > qt){ rem -= (qt+1); ++qt; }
  int ct = rem;                  // 0..qt
  int t0 = ct*64;

  int kvh  = h >> 1;
  int w    = threadIdx.x >> 6;
  int lane = threadIdx.x & 63;
  int lg   = lane >> 4;
  int lc   = lane & 15;

  #pragma unroll
  for(int sub=0; sub<4; ++sub){
    int rr = w*16 + sub*4 + lg;
    int sw = ((lc ^ (rr>>2)) & 15)*4;
    *(float4*)&QPsh[rr*68 + lc*4] =
      *(const float4*)&qn[(size_t)(qt*64+rr)*CEMB + h*HD + lc*4];
    *(float4*)&Ksh[rr*64 + sw] =
      *(const float4*)&kn[(size_t)(t0+rr)*KVC + kvh*HD + lc*4];
    *(float4*)&Vsh[rr*64 + sw] =
      *(const float4*)&vr[(size_t)(t0+rr)*KVC + kvh*HD + lc*4];
  }
  __syncthreads();

  float s[4][4];
  #pragma unroll
  for(int r=0;r<4;r++)
    #pragma unroll
    for(int c=0;c<4;c++) s[r][c] = -INFINITY;

  #pragma unroll
  for(int dg=0; dg<16; ++dg){
    float4 k4[4], q4[4];
    int ksw = ((dg ^ lc)&15)*4;
    #pragma unroll
    for(int c=0;c<4;c++)
      k4[c] = *(const float4*)&Ksh[(lc*4+c)*64 + ksw];
    #pragma unroll
    for(int r=0;r<4;r++)
      q4[r] = *(const float4*)&QPsh[(w*16+lg*4+r)*68 + dg*4];
    #pragma unroll
    for(int r=0;r<4;r++)
      #pragma unroll
      for(int c=0;c<4;c++)
        s[r][c] = fmaxf(s[r][c],
                  fmaxf(fmaxf(q4[r].x + k4[c].x, q4[r].y + k4[c].y),
                        fmaxf(q4[r].z + k4[c].z, q4[r].w + k4[c].w)));
  }

  float mrow[4], lrow[4];
  #pragma unroll
  for(int r=0;r<4;r++){
    int i = qt*64 + w*16 + lg*4 + r;
    #pragma unroll
    for(int c=0;c<4;c++)
      if (t0 + lc*4 + c > i) s[r][c] = -INFINITY;   // causal mask
    float mt = fmaxf(fmaxf(s[r][0],s[r][1]), fmaxf(s[r][2],s[r][3]));
    mt = fmaxf(mt, __shfl_xor(mt,1));
    mt = fmaxf(mt, __shfl_xor(mt,2));
    mt = fmaxf(mt, __shfl_xor(mt,4));
    mt = fmaxf(mt, __shfl_xor(mt,8));
    float p0 = __expf(s[r][0]-mt), p1 = __expf(s[r][1]-mt);
    float p2 = __expf(s[r][2]-mt), p3 = __expf(s[r][3]-mt);
    float ps = p0+p1+p2+p3;
    ps += __shfl_xor(ps,1); ps += __shfl_xor(ps,2);
    ps += __shfl_xor(ps,4); ps += __shfl_xor(ps,8);
    mrow[r] = mt; lrow[r] = ps;
    *(float4*)&QPsh[(w*16+lg*4+r)*68 + lc*4] = make_float4(p0,p1,p2,p3);
  }
  __builtin_amdgcn_wave_barrier();   // DS in-order per wave; rows wave-private

  float acc[4][4];
  #pragma unroll
  for(int r=0;r<4;r++)
    #pragma unroll
    for(int c=0;c<4;c++) acc[r][c] = 0.f;

  #pragma unroll
  for(int jg=0; jg<16; ++jg){
    float4 v4[4], p4[4];
    int vsw = ((lc ^ jg)&15)*4;
    #pragma unroll
    for(int jj=0;jj<4;jj++)
      v4[jj] = *(const float4*)&Vsh[(jg*4+jj)*64 + vsw];
    #pragma unroll
    for(int r=0;r<4;r++)
      p4[r] = *(const float4*)&QPsh[(w*16+lg*4+r)*68 + jg*4];
    #pragma unroll
    for(int r=0;r<4;r++)
      #pragma unroll
      for(int c=0;c<4;c++)
        acc[r][c] = fmaf(p4[r].x, (&v4[0].x)[c], fmaf(p4[r].y, (&v4[1].x)[c],
                    fmaf(p4[r].z, (&v4[2].x)[c], fmaf(p4[r].w, (&v4[3].x)[c], acc[r][c]))));
  }

  #pragma unroll
  for(int r=0;r<4;r++){
    int i = qt*64 + w*16 + lg*4 + r;
    int pidx = (h*TT + i)*8 + ct;
    *(uint2*)&part_acc[(size_t)pidx*64 + lc*4] =
      make_uint2(pack_bf16(acc[r][0],acc[r][1]), pack_bf16(acc[r][2],acc[r][3]));
    if (lc == 0) part_ml[pidx] = make_float2(mrow[r], lrow[r]);
  }
}

// ============================================================================
// K3: merge <=8 bf16 chunk partials per (h,row) -> yF bf16 A-fragments.
// (R12-proven batched-load structure; loads are now 2B bf16.)
// ============================================================================
__global__ void __launch_bounds__(256) attn_reduce(const unsigned short* __restrict__ part_acc,
    const float2* __restrict__ part_ml, unsigned short* __restrict__ yF){
  int wid  = (blockIdx.x * blockDim.x + threadIdx.x) >> 6;  // 0..6143
  int lane = threadIdx.x & 63;
  int h = wid >> 9;
  int i = wid & 511;
  int nch = (i >> 6) + 1;       // wave-uniform
  int base = (h*TT + i)*8;

  float2 mls[8]; float acs[8];
  #pragma unroll
  for(int c=0;c<8;c++){
    mls[c] = part_ml[base + c];
    acs[c] = bf16_to_f32(part_acc[(size_t)(base + c)*64 + lane]);
  }

  float m = -INFINITY, l = 0.f, a = 0.f;
  #pragma unroll
  for(int c=0;c<8;c++){
    if (c < nch){
      float m_new = fmaxf(m, mls[c].x);
      float sa  = __expf(m - m_new);
      float sc_ = __expf(mls[c].x - m_new);
      l = l*sa + mls[c].y*sc_;
      a = a*sa + acs[c]*sc_;
      m = m_new;
    }
  }
  float val = a / l;
  int s = i>>4, rr = i&15;
  int ks = h*2 + (lane>>5), q2 = (lane>>3)&3, j = lane&7;
  yF[ (((size_t)(s*24 + ks)*64 + q2*16 + rr)<<3) + j ] = bf16_rn(val);
}

// ============================================================================
// K4: proj GEMM, fragment-direct, 192 blocks (8mt x 24 ntH of 32 cols).
// (R12-proven)
// ============================================================================
__global__ void __launch_bounds__(256) gemm_proj_mfma(
    const unsigned short* __restrict__ yF, const unsigned short* __restrict__ WpF,
    float* __restrict__ out){
  int bx = blockIdx.x;           // 0..191
  int mt = bx / 24, ntH = bx % 24;
  int tid = threadIdx.x, w = tid>>6, lane = tid&63, qq = lane>>4, r = lane&15;
  int s = mt*4 + w;   // 16-row strip

  const short8* Af = (const short8*)yF  + (size_t)s*24*64 + lane;
  const short8* Bf = (const short8*)WpF + lane;

  floatx4 acc[2];
  acc[0] = (floatx4){0.f,0.f,0.f,0.f};
  acc[1] = (floatx4){0.f,0.f,0.f,0.f};

  short8 ac_ = Af[0];
  short8 bc_[2];
  #pragma unroll
  for(int c=0;c<2;c++) bc_[c] = Bf[(size_t)((ntH*2+c)*24)*64];

  for(int ks=0; ks<24; ++ks){
    short8 an; short8 bn[2];
    if (ks < 23){
      an = Af[(size_t)(ks+1)*64];
      #pragma unroll
      for(int c=0;c<2;c++) bn[c] = Bf[(size_t)((ntH*2+c)*24 + ks+1)*64];
    }
    #pragma unroll
    for(int c=0;c<2;c++)
      acc[c] = __builtin_amdgcn_mfma_f32_16x16x32_bf16(ac_, bc_[c], acc[c], 0,0,0);
    if (ks < 23){
      ac_ = an;
      #pragma unroll
      for(int c=0;c<2;c++) bc_[c] = bn[c];
    }
  }

  #pragma unroll
  for(int reg=0; reg<4; ++reg){
    int t = mt*64 + w*16 + qq*4 + reg;
    float* dst = out + (size_t)t*CEMB + ntH*32;
    #pragma unroll
    for(int c=0;c<2;c++)
      dst[c*16 + r] = acc[c][reg];
  }
}

extern "C" void kernel_launch(void* const* d_in, const int* in_sizes, int n_in,
                              void* d_out, int out_size, void* d_ws, size_t ws_size,
                              hipStream_t stream){
  const float* x    = (const float*)d_in[0];
  const float* cosb = (const float*)d_in[1];
  const float* sinb = (const float*)d_in[2];
  const float* Wq   = (const float*)d_in[3];
  const float* Wk   = (const float*)d_in[4];
  const float* Wv   = (const float*)d_in[5];
  const float* Wp   = (const float*)d_in[6];
  float* out = (float*)d_out;

  float* ws        = (float*)d_ws;
  float* q_raw     = ws;                                // 512*768 f32
  float* k_raw     = q_raw + (size_t)TT*CEMB;           // 512*384 f32
  float* v_raw     = k_raw + (size_t)TT*KVC;            // 512*384 f32
  unsigned short* part_acc = (unsigned short*)(v_raw + (size_t)TT*KVC); // 12*512*8*64 bf16
  float2* part_ml  = (float2*)(part_acc + (size_t)NH*TT*8*64);          // 12*512*8
  unsigned short* WpF = (unsigned short*)(part_ml + (size_t)NH*TT*8);   // 48*24*64*8
  unsigned short* yF  = WpF + (size_t)48*24*64*8;       // 32*24*64*8

  gemm_qkv_mfma <<<dim3(228),   256, 0, stream>>>(x, Wq, Wk, Wv, Wp, cosb, sinb,
                                                  q_raw, k_raw, v_raw, WpF);
  attn_tile     <<<dim3(36,NH), 256, 0, stream>>>(q_raw, k_raw, v_raw, part_acc, part_ml);
  attn_reduce   <<<dim3(NH*TT/4), 256, 0, stream>>>(part_acc, part_ml, yF);
  gemm_proj_mfma<<<dim3(192),   256, 0, stream>>>(yF, WpF, out);
}